// Round 1
// baseline (183.531 us; speedup 1.0000x reference)
//
#include <hip/hip_runtime.h>

#define D     2048
#define NEXP  4
#define BLK   256
#define NWAVE 4
#define EPSV  1e-5f

__global__ __launch_bounds__(BLK) void hc_kernel(
    const float* __restrict__ lo,       // [tok, D]
    const float* __restrict__ hs,       // [tok, NEXP, D]
    const float* __restrict__ Bm,       // [1, NEXP]
    const float* __restrict__ Am,      // [NEXP, 1]
    const float* __restrict__ Ar,      // [NEXP, NEXP]
    const float* __restrict__ s_alpha, // [NEXP, NEXP]
    const float* __restrict__ s_beta,  // [1, NEXP]
    const float* __restrict__ Wb,      // [D, NEXP]
    const float* __restrict__ Wm,      // [D, NEXP]
    const float* __restrict__ Wr,      // [D, NEXP, NEXP]
    float* __restrict__ out)           // [tok, NEXP, D]
{
    __shared__ float h_lds[NEXP][D];       // 32 KB
    __shared__ float red[NWAVE][24];
    __shared__ float stats[2][NEXP];
    __shared__ float coef[24];

    const int tid  = threadIdx.x;
    const int wave = tid >> 6;
    const int lane = tid & 63;
    const long tok = blockIdx.x;

    const float4* hs4  = (const float4*)(hs + tok * (long)(NEXP * D));
    const float4* lo4  = (const float4*)(lo + tok * (long)D);
    float4*       out4 = (float4*)(out + tok * (long)(NEXP * D));

    // ---- Phase 1: stage hidden row in LDS, accumulate sum / sumsq per n ----
    float sum[NEXP], sq[NEXP];
    #pragma unroll
    for (int n = 0; n < NEXP; ++n) { sum[n] = 0.f; sq[n] = 0.f; }

    #pragma unroll
    for (int n = 0; n < NEXP; ++n) {
        #pragma unroll
        for (int k = 0; k < D / 4 / BLK; ++k) {     // 2 iters
            int d4 = tid + BLK * k;
            float4 v = hs4[n * (D / 4) + d4];
            sum[n] += v.x + v.y + v.z + v.w;
            sq[n]  += v.x * v.x + v.y * v.y + v.z * v.z + v.w * v.w;
            ((float4*)h_lds[n])[d4] = v;
        }
    }
    // wave-level reduce of 8 values
    #pragma unroll
    for (int n = 0; n < NEXP; ++n) {
        #pragma unroll
        for (int off = 32; off > 0; off >>= 1) {
            sum[n] += __shfl_down(sum[n], off, 64);
            sq[n]  += __shfl_down(sq[n],  off, 64);
        }
    }
    if (lane == 0) {
        #pragma unroll
        for (int n = 0; n < NEXP; ++n) {
            red[wave][n]        = sum[n];
            red[wave][NEXP + n] = sq[n];
        }
    }
    __syncthreads();
    if (tid < NEXP) {
        float s = 0.f, s2 = 0.f;
        for (int w = 0; w < NWAVE; ++w) { s += red[w][tid]; s2 += red[w][NEXP + tid]; }
        float mu  = s * (1.f / D);
        float var = s2 * (1.f / D) - mu * mu;
        stats[0][tid] = mu;
        stats[1][tid] = rsqrtf(var + EPSV);
    }
    __syncthreads();
    float mu[NEXP], rs[NEXP];
    #pragma unroll
    for (int n = 0; n < NEXP; ++n) { mu[n] = stats[0][n]; rs[n] = stats[1][n]; }

    // ---- Phase 2: H_bar dot-products against the 24 weight columns ----
    float acc[24];
    #pragma unroll
    for (int v = 0; v < 24; ++v) acc[v] = 0.f;

    const float4* Wb4 = (const float4*)Wb;
    const float4* Wm4 = (const float4*)Wm;
    const float4* Wr4 = (const float4*)Wr;

    #pragma unroll
    for (int k = 0; k < D / BLK; ++k) {             // 8 iters
        int d = tid + BLK * k;
        float hb = 0.f;
        #pragma unroll
        for (int n = 0; n < NEXP; ++n) hb += (h_lds[n][d] - mu[n]) * rs[n];
        hb *= 0.25f;

        float4 wb = Wb4[d];
        acc[0] += hb * wb.x; acc[1] += hb * wb.y; acc[2] += hb * wb.z; acc[3] += hb * wb.w;
        float4 wm = Wm4[d];
        acc[4] += hb * wm.x; acc[5] += hb * wm.y; acc[6] += hb * wm.z; acc[7] += hb * wm.w;
        #pragma unroll
        for (int i = 0; i < NEXP; ++i) {
            float4 wr = Wr4[d * 4 + i];
            acc[8 + i * 4 + 0] += hb * wr.x;
            acc[8 + i * 4 + 1] += hb * wr.y;
            acc[8 + i * 4 + 2] += hb * wr.z;
            acc[8 + i * 4 + 3] += hb * wr.w;
        }
    }
    #pragma unroll
    for (int v = 0; v < 24; ++v) {
        #pragma unroll
        for (int off = 32; off > 0; off >>= 1)
            acc[v] += __shfl_down(acc[v], off, 64);
    }
    if (lane == 0) {
        #pragma unroll
        for (int v = 0; v < 24; ++v) red[wave][v] = acc[v];
    }
    __syncthreads();
    if (tid < 24) {
        float s = 0.f;
        for (int w = 0; w < NWAVE; ++w) s += red[w][tid];
        float t = tanhf(s);
        float c;
        if (tid < 4) {
            c = s_beta[tid] * t + Bm[tid];
        } else if (tid < 8) {
            int n = tid - 4;
            c = s_alpha[n * 4] * t + Am[n];
        } else {
            int ij = tid - 8;
            c = s_alpha[ij] * t + Ar[ij];
        }
        coef[tid] = c;
    }
    __syncthreads();

    float Bd[NEXP], Amd[NEXP], Ard[NEXP][NEXP];
    #pragma unroll
    for (int n = 0; n < NEXP; ++n) { Bd[n] = coef[n]; Amd[n] = coef[4 + n]; }
    #pragma unroll
    for (int i = 0; i < NEXP; ++i)
        #pragma unroll
        for (int j = 0; j < NEXP; ++j) Ard[i][j] = coef[8 + i * 4 + j];

    // ---- Phase 3: outputs ----
    #pragma unroll
    for (int k = 0; k < D / 4 / BLK; ++k) {         // 2 iters
        int d4 = tid + BLK * k;
        float4 h[NEXP];
        #pragma unroll
        for (int n = 0; n < NEXP; ++n) h[n] = ((const float4*)h_lds[n])[d4];
        float4 l = lo4[d4];

        float4 mx = {0.f, 0.f, 0.f, 0.f};
        #pragma unroll
        for (int n = 0; n < NEXP; ++n) {
            mx.x += Amd[n] * h[n].x; mx.y += Amd[n] * h[n].y;
            mx.z += Amd[n] * h[n].z; mx.w += Amd[n] * h[n].w;
        }
        #pragma unroll
        for (int i = 0; i < NEXP; ++i) {
            float4 o;
            o.x = Bd[i] * l.x + mx.x;
            o.y = Bd[i] * l.y + mx.y;
            o.z = Bd[i] * l.z + mx.z;
            o.w = Bd[i] * l.w + mx.w;
            #pragma unroll
            for (int j = 0; j < NEXP; ++j) {
                o.x += Ard[i][j] * h[j].x;
                o.y += Ard[i][j] * h[j].y;
                o.z += Ard[i][j] * h[j].z;
                o.w += Ard[i][j] * h[j].w;
            }
            out4[i * (D / 4) + d4] = o;
        }
    }
}

extern "C" void kernel_launch(void* const* d_in, const int* in_sizes, int n_in,
                              void* d_out, int out_size, void* d_ws, size_t ws_size,
                              hipStream_t stream) {
    const float* lo      = (const float*)d_in[0];
    const float* hs      = (const float*)d_in[1];
    const float* Bm      = (const float*)d_in[2];
    const float* Am      = (const float*)d_in[3];
    const float* Ar      = (const float*)d_in[4];
    const float* s_alpha = (const float*)d_in[5];
    const float* s_beta  = (const float*)d_in[6];
    const float* Wb      = (const float*)d_in[7];
    const float* Wm      = (const float*)d_in[8];
    const float* Wr      = (const float*)d_in[9];
    float* out = (float*)d_out;

    const int tokens = in_sizes[0] / D;   // 4 * 2048 = 8192
    hc_kernel<<<tokens, BLK, 0, stream>>>(lo, hs, Bm, Am, Ar, s_alpha, s_beta,
                                          Wb, Wm, Wr, out);
}